// Round 13
// baseline (146.205 us; speedup 1.0000x reference)
//
#include <hip/hip_runtime.h>
#include <hip/hip_bf16.h>

typedef __attribute__((ext_vector_type(4))) float f32x4;
typedef __attribute__((ext_vector_type(8))) short bf16x8;

#define NROWS 32768
#define DIM   2048
#define NEXP  64
#define BKF   128            // K-chunk (f32 elements)
#define NCH   16             // chunks per 32-row tile
#define NTILE 2              // tiles per block
#define NM    (NCH * NTILE)  // 32 sim chunk-iterations
#define NITER (NM + NCH)     // + 16 tail iterations (moe of last tile)

__device__ __forceinline__ short f2bf(float f) {
    __hip_bfloat16 h = __float2bfloat16(f);   // RTNE
    short s;
    __builtin_memcpy(&s, &h, 2);
    return s;
}

// async global->LDS DMA, 16B/lane; LDS dest wave-uniform (HW adds lane*16).
__device__ __forceinline__ void async16(const void* g, void* l) {
    __builtin_amdgcn_global_load_lds(
        (const __attribute__((address_space(1))) unsigned int*)g,
        (__attribute__((address_space(3))) unsigned int*)l, 16, 0, 0);
}

// ---------------- Kernel A: expert prep -------------------------------------
__global__ __launch_bounds__(256) void prep_experts(
    const float* __restrict__ ek,
    short* __restrict__ ekbf,
    short* __restrict__ ekT,
    float* __restrict__ enorm)
{
    const int e = blockIdx.x;
    const int t = threadIdx.x;
    const float* row = ek + e * DIM;
    float ss = 0.f;
#pragma unroll
    for (int i = 0; i < 2; ++i) {
        const int c4 = t + i * 256;
        const float4 v = ((const float4*)row)[c4];
        ss += v.x * v.x + v.y * v.y + v.z * v.z + v.w * v.w;
        short4 b;
        b.x = f2bf(v.x); b.y = f2bf(v.y); b.z = f2bf(v.z); b.w = f2bf(v.w);
        *(short4*)(ekbf + e * DIM + c4 * 4) = b;
        const int d = c4 * 4;
        ekT[(d + 0) * NEXP + e] = b.x;
        ekT[(d + 1) * NEXP + e] = b.y;
        ekT[(d + 2) * NEXP + e] = b.z;
        ekT[(d + 3) * NEXP + e] = b.w;
    }
#pragma unroll
    for (int s = 1; s < 64; s <<= 1) ss += __shfl_xor(ss, s);
    __shared__ float red[4];
    if ((t & 63) == 0) red[t >> 6] = ss;
    __syncthreads();
    if (t == 0) enorm[e] = sqrtf(red[0] + red[1] + red[2] + red[3]);
}

// ---------------- Fused wave-specialized kernel ------------------------------
// 64 rows/block (2 tiles of 32), grid 512 = 2 blocks/CU. Waves 0-1 = sim crew
// (DMA-only vmem: clean counted vmcnt). Waves 2-3 = moe crew (softmax, out_sim,
// W@ekT MFMA, out_wei stores; compiler-managed loads in their own FIFO).
// Pipeline: sim(t0) | sim(t1)+moe(t0) | moe(t1). Raw s_barrier + lgkmcnt(0)
// handoffs only (never __syncthreads -> would drain vmcnt).
__global__ __launch_bounds__(256) void cosmoe_ws(
    const float* __restrict__ z,
    const short* __restrict__ ekbf,   // [64][2048] bf16
    const short* __restrict__ ekT,    // [2048][64] bf16
    const float* __restrict__ enorm,  // [64]
    float* __restrict__ out_sim,      // [32768][64]
    float* __restrict__ out_wei)      // [32768][2048]
{
    const int tid = threadIdx.x;
    const int w   = tid >> 6;
    const int l   = tid & 63;
    const int lr  = l & 15;
    const int lg  = l >> 4;
    const int base = blockIdx.x * 64;
    const bool simCrew = (w < 2);
    const int ws = w;        // sim crew wave index (0,1)
    const int wm = w - 2;    // moe crew wave index (0,1)

    __shared__ __align__(16) float zbuf[2][32][BKF];   // 32 KiB
    __shared__ __align__(16) short ebuf[2][64][BKF];   // 32 KiB
    __shared__ __align__(16) float simL[32][64];       // 8 KiB (raw dots)
    __shared__ __align__(16) short WL[32][64];         // 4 KiB (softmax bf16, swizzled)
    __shared__ float znL[32];

    // sim-crew state: acc[mt][nt] covers rows 0..31 x experts ws*32..+31
    f32x4 acc[2][2];
#pragma unroll
    for (int a = 0; a < 2; ++a)
#pragma unroll
        for (int b2 = 0; b2 < 2; ++b2) acc[a][b2] = f32x4{0.f, 0.f, 0.f, 0.f};
    float ss0 = 0.f, ss1 = 0.f;
    // moe-crew state
    bf16x8 afr[2][2];

    // stage chunk m_ (tile m_>>4, K-chunk m_&15) into buffer m_&1.
    // sim wave ws: z rows ws*16..+15 (2 rows/instr, 512B spans),
    //              ek rows ws*32..+31 (4 rows/instr, 256B spans). 16 DMA/wave.
    auto STAGE = [&](int m_) {
        const int b_ = m_ & 1;
        const int c_ = m_ & 15;
        const size_t rb = (size_t)(base + (m_ >> 4) * 32);
#pragma unroll
        for (int i = 0; i < 8; ++i) {
            const int r0 = ws * 16 + i * 2;
            const int zr = r0 + (l >> 5);
            async16(z + (rb + zr) * DIM + c_ * BKF + (((l & 31) ^ (zr & 7)) << 2),
                    &zbuf[b_][r0][0]);
        }
#pragma unroll
        for (int i = 0; i < 8; ++i) {
            const int r0 = ws * 32 + i * 4;
            const int er = r0 + (l >> 4);
            async16(ekbf + (size_t)er * DIM + c_ * BKF + (((l & 15) ^ (er & 7)) << 3),
                    &ebuf[b_][r0][0]);
        }
    };

    // moe slice: tile t, slice s (32 cols). Uses afr regs; compiler loads ekT.
    auto MOESLICE = [&](int t, int s) {
        const int d0 = wm * 1024 + s * 32;
        const size_t rb = (size_t)(base + t * 32);
        f32x4 oacc[2][2];
#pragma unroll
        for (int nt2 = 0; nt2 < 2; ++nt2) {
            const short* bp = ekT + (size_t)(d0 + nt2 * 16 + lr) * NEXP + lg * 8;
            const bf16x8 b0 = *(const bf16x8*)bp;
            const bf16x8 b1 = *(const bf16x8*)(bp + 32);
#pragma unroll
            for (int mt = 0; mt < 2; ++mt) {
                f32x4 o = f32x4{0.f, 0.f, 0.f, 0.f};
                o = __builtin_amdgcn_mfma_f32_16x16x32_bf16(afr[mt][0], b0, o, 0, 0, 0);
                o = __builtin_amdgcn_mfma_f32_16x16x32_bf16(afr[mt][1], b1, o, 0, 0, 0);
                oacc[nt2][mt] = o;
            }
        }
#pragma unroll
        for (int nt2 = 0; nt2 < 2; ++nt2)
#pragma unroll
            for (int mt = 0; mt < 2; ++mt)
#pragma unroll
                for (int j = 0; j < 4; ++j)
                    out_wei[(rb + mt * 16 + lg * 4 + j) * DIM + d0 + nt2 * 16 + lr]
                        = oacc[nt2][mt][j];
    };

    if (simCrew) { STAGE(0); STAGE(1); }   // 32 DMAs/wave in flight

#pragma unroll 1
    for (int m = 0; m < NITER; ++m) {
        const bool simAct = m < NM;
        if (simCrew && simAct) {
            if (m < NM - 1) asm volatile("s_waitcnt vmcnt(16)" ::: "memory");
            else            asm volatile("s_waitcnt vmcnt(0)"  ::: "memory");
        }
        __builtin_amdgcn_s_barrier();
        __builtin_amdgcn_sched_barrier(0);

        if (simCrew && simAct) {
            const int b = m & 1;
#pragma unroll
            for (int kk = 0; kk < 4; ++kk) {
                bf16x8 af[2];
#pragma unroll
                for (int mt = 0; mt < 2; ++mt) {
                    const char* zp = (const char*)&zbuf[b][mt * 16 + lr][0];
                    const float4 a0 = *(const float4*)(zp + (((kk * 8 + lg * 2)     ^ (lr & 7)) << 4));
                    const float4 a1 = *(const float4*)(zp + (((kk * 8 + lg * 2 + 1) ^ (lr & 7)) << 4));
                    if (mt == ws) {   // each sim wave owns ssq of its 16 rows
                        ss0 = fmaf(a0.x, a0.x, ss0); ss1 = fmaf(a0.y, a0.y, ss1);
                        ss0 = fmaf(a0.z, a0.z, ss0); ss1 = fmaf(a0.w, a0.w, ss1);
                        ss0 = fmaf(a1.x, a1.x, ss0); ss1 = fmaf(a1.y, a1.y, ss1);
                        ss0 = fmaf(a1.z, a1.z, ss0); ss1 = fmaf(a1.w, a1.w, ss1);
                    }
                    af[mt][0] = f2bf(a0.x); af[mt][1] = f2bf(a0.y);
                    af[mt][2] = f2bf(a0.z); af[mt][3] = f2bf(a0.w);
                    af[mt][4] = f2bf(a1.x); af[mt][5] = f2bf(a1.y);
                    af[mt][6] = f2bf(a1.z); af[mt][7] = f2bf(a1.w);
                }
#pragma unroll
                for (int nt = 0; nt < 2; ++nt) {
                    const int er = ws * 32 + nt * 16 + lr;
                    const bf16x8 bf = *(const bf16x8*)((const char*)&ebuf[b][er][0]
                                        + (((kk * 4 + lg) ^ (lr & 7)) << 4));
                    acc[0][nt] = __builtin_amdgcn_mfma_f32_16x16x32_bf16(af[0], bf, acc[0][nt], 0, 0, 0);
                    acc[1][nt] = __builtin_amdgcn_mfma_f32_16x16x32_bf16(af[1], bf, acc[1][nt], 0, 0, 0);
                }
            }
        }
        if (!simCrew && m >= NCH) {       // moe slices for tile (m-16)>>4
            const int t  = (m - NCH) >> 4;
            const int s0 = ((m - NCH) & 15) * 2;
            MOESLICE(t, s0);
            MOESLICE(t, s0 + 1);
        }
        asm volatile("s_waitcnt lgkmcnt(0)" ::: "memory");
        __builtin_amdgcn_s_barrier();
        if (simCrew && simAct && m + 2 < NM) STAGE(m + 2);

        // ---- tile boundary: epilogue -> softmax -> afr ----
        if (simAct && (m & 15) == 15) {
            const int t = m >> 4;
            if (simCrew) {
                float ssq = ss0 + ss1;
                ssq += __shfl_xor(ssq, 16);
                ssq += __shfl_xor(ssq, 32);
                if (l < 16) znL[ws * 16 + l] = sqrtf(ssq);
#pragma unroll
                for (int mt = 0; mt < 2; ++mt)
#pragma unroll
                    for (int nt = 0; nt < 2; ++nt)
#pragma unroll
                        for (int j = 0; j < 4; ++j)
                            simL[mt * 16 + lg * 4 + j][ws * 32 + nt * 16 + lr] = acc[mt][nt][j];
#pragma unroll
                for (int a = 0; a < 2; ++a)
#pragma unroll
                    for (int b2 = 0; b2 < 2; ++b2) acc[a][b2] = f32x4{0.f, 0.f, 0.f, 0.f};
                ss0 = 0.f; ss1 = 0.f;
            }
            asm volatile("s_waitcnt lgkmcnt(0)" ::: "memory");
            __builtin_amdgcn_s_barrier();
            if (!simCrew) {
                // softmax: thread -> row r (4 threads/row), experts cc*16..+16
                const int local = wm * 64 + l;
                const int r  = local >> 2;
                const int cc = local & 3;
                float sv[16];
                const float zn = znL[r];
#pragma unroll
                for (int i = 0; i < 16; ++i) {
                    const float en = enorm[cc * 16 + i];
                    sv[i] = simL[r][cc * 16 + i] / fmaxf(zn * en, 1e-8f);
                }
                float* op = out_sim + (size_t)(base + t * 32 + r) * NEXP + cc * 16;
#pragma unroll
                for (int i = 0; i < 4; ++i) {
                    float4 v;
                    v.x = sv[i*4]; v.y = sv[i*4+1]; v.z = sv[i*4+2]; v.w = sv[i*4+3];
                    *(float4*)(op + i * 4) = v;
                }
                float mx = sv[0];
#pragma unroll
                for (int i = 1; i < 16; ++i) mx = fmaxf(mx, sv[i]);
                mx = fmaxf(mx, __shfl_xor(mx, 1));
                mx = fmaxf(mx, __shfl_xor(mx, 2));
                float sum = 0.f;
#pragma unroll
                for (int i = 0; i < 16; ++i) { sv[i] = __expf(sv[i] - mx); sum += sv[i]; }
                sum += __shfl_xor(sum, 1);
                sum += __shfl_xor(sum, 2);
                const float inv = 1.0f / sum;
                bf16x8 w0, w1;
#pragma unroll
                for (int i = 0; i < 8; ++i) {
                    w0[i] = f2bf(sv[i] * inv);
                    w1[i] = f2bf(sv[8 + i] * inv);
                }
                *(bf16x8*)&WL[r][((cc * 2)     ^ (r & 7)) * 8] = w0;
                *(bf16x8*)&WL[r][((cc * 2 + 1) ^ (r & 7)) * 8] = w1;
            }
            asm volatile("s_waitcnt lgkmcnt(0)" ::: "memory");
            __builtin_amdgcn_s_barrier();
            if (!simCrew) {
#pragma unroll
                for (int mt = 0; mt < 2; ++mt)
#pragma unroll
                    for (int ks = 0; ks < 2; ++ks) {
                        const int row = mt * 16 + lr;
                        const int u   = (ks * 4 + lg) ^ (row & 7);
                        afr[mt][ks] = *(const bf16x8*)&WL[row][u * 8];
                    }
            }
        }
    }
}

// ---------------- launch -----------------------------------------------------
extern "C" void kernel_launch(void* const* d_in, const int* in_sizes, int n_in,
                              void* d_out, int out_size, void* d_ws, size_t ws_size,
                              hipStream_t stream) {
    const float* z  = (const float*)d_in[0];
    const float* ek = (const float*)d_in[1];
    float* out_sim = (float*)d_out;
    float* out_wei = out_sim + (size_t)NROWS * NEXP;

    short* ekbf  = (short*)d_ws;                 // 256 KiB
    short* ekT   = ekbf + NEXP * DIM;            // 256 KiB
    float* enorm = (float*)(ekT + DIM * NEXP);   // 256 B

    prep_experts<<<NEXP, 256, 0, stream>>>(ek, ekbf, ekT, enorm);
    cosmoe_ws<<<NROWS / 64, 256, 0, stream>>>(z, ekbf, ekT, enorm, out_sim, out_wei);
}